// Round 19
// baseline (1808.584 us; speedup 1.0000x reference)
//
#include <hip/hip_runtime.h>
#include <cmath>

#define BATCH  2
#define SEQ    2048
#define DMODEL 1024
#define NHEAD  16
#define HDIM   64
#define KTOP   8
#define KKEEP  10   // global top-8 + slack for bitwise ties at the threshold
#define LKEEP  12   // lane-local FMA-prefilter candidates (margin vs delta)

// KC=512 CONFIRMED bit-exact vs harness numpy reference (rounds 6/8-17 pass).
#define KC_PANEL 512

// ---------------------------------------------------------------------------
// Projection GEMM replicating OpenBLAS sgemm fp32 rounding (KC=512 panels).
// MODE 0: out in head layout [b][h][s][d]; MODE 1: flat [row][col].
// ---------------------------------------------------------------------------
template<int MODE>
__global__ __launch_bounds__(256)
void proj_gemm(const float* __restrict__ A, const float* __restrict__ W,
               const float* __restrict__ bias, float* __restrict__ outp)
{
    __shared__ float As[32][68];   // [k][m]
    __shared__ float Bs[32][68];   // [k][n]
    const int tid  = threadIdx.x;
    const int tx   = tid & 15, ty = tid >> 4;
    const int row0 = blockIdx.x * 64;
    const int col0 = blockIdx.y * 64;
    const int lm   = tid >> 2;          // 0..63
    const int lk   = (tid & 3) * 8;     // 0,8,16,24

    float acc[4][4] = {};   // open panel chain
    float sum[4][4] = {};   // closed panels

    for (int kb = 0; kb < DMODEL; kb += 32) {
        if (kb && (kb % KC_PANEL == 0)) {
            #pragma unroll
            for (int i = 0; i < 4; ++i)
                #pragma unroll
                for (int j = 0; j < 4; ++j) { sum[i][j] += acc[i][j]; acc[i][j] = 0.f; }
        }
        __syncthreads();
        const float* srcA = A + (size_t)(row0 + lm) * DMODEL + kb + lk;
        float4 a0 = *(const float4*)srcA;
        float4 a1 = *(const float4*)(srcA + 4);
        const float* srcB = W + (size_t)(col0 + lm) * DMODEL + kb + lk;
        float4 b0 = *(const float4*)srcB;
        float4 b1 = *(const float4*)(srcB + 4);
        As[lk+0][lm]=a0.x; As[lk+1][lm]=a0.y; As[lk+2][lm]=a0.z; As[lk+3][lm]=a0.w;
        As[lk+4][lm]=a1.x; As[lk+5][lm]=a1.y; As[lk+6][lm]=a1.z; As[lk+7][lm]=a1.w;
        Bs[lk+0][lm]=b0.x; Bs[lk+1][lm]=b0.y; Bs[lk+2][lm]=b0.z; Bs[lk+3][lm]=b0.w;
        Bs[lk+4][lm]=b1.x; Bs[lk+5][lm]=b1.y; Bs[lk+6][lm]=b1.z; Bs[lk+7][lm]=b1.w;
        __syncthreads();
        #pragma unroll
        for (int kk = 0; kk < 32; ++kk) {   // ascending k, fused-FMA chain
            float4 af = *(const float4*)&As[kk][ty*4];
            float4 bf = *(const float4*)&Bs[kk][tx*4];
            float a_[4] = {af.x, af.y, af.z, af.w};
            float b_[4] = {bf.x, bf.y, bf.z, bf.w};
            #pragma unroll
            for (int i = 0; i < 4; ++i)
                #pragma unroll
                for (int j = 0; j < 4; ++j)
                    acc[i][j] = fmaf(a_[i], b_[j], acc[i][j]);
        }
    }

    #pragma unroll
    for (int i = 0; i < 4; ++i) {
        const int row = row0 + ty*4 + i;
        const int bb  = row >> 11;
        const int ss  = row & (SEQ - 1);
        #pragma unroll
        for (int j = 0; j < 4; ++j) {
            const int col = col0 + tx*4 + j;
            float r = sum[i][j] + acc[i][j];   // close final panel
            r = r + bias[col];                 // bias == 0.0f: exact
            if constexpr (MODE == 1) {
                outp[(size_t)row * DMODEL + col] = r;
            } else {
                const int h = col >> 6, d = col & 63;
                outp[(((size_t)(bb*NHEAD + h))*SEQ + ss)*HDIM + d] = r;
            }
        }
    }
}

// ---------------------------------------------------------------------------
// Attention, lane = query row, waves split keys 4-way, 2 waves/SIMD.
// R18 change vs R17 (which was otherwise identical): LAUNDER the scan's K
// pointer through a VGPR (asm "+v") so the wave-uniform loads emit as
// global_load_dwordx4 (VMEM) instead of s_load.
//   Diagnosis from R14/16/17 convergence at ~1100us + SGPR=112: the compiler
//   scalarized K loads; scalar loads return OUT-OF-ORDER so only
//   lgkmcnt(0) full drains are legal -> no prefetch possible, and the
//   per-CU scalar cache serializes all 8 waves' streaming misses (2x
//   occupancy changed nothing, VALUBusy pinned at 51%). VMEM gives per-wave
//   vmcnt partial waits + deep miss queues; uniform addresses coalesce to
//   one XCD-L2 transaction (~200cyc), hidden by the other wave's ~290cyc
//   compute. Rescore gathers (fi[s] per-lane) were already vector.
// Scan = FMA prefilter (lane-local top-LKEEP); rescore = exact npyv cascade
// fused with canonical insert, sched_barrier-fenced; exact 4-way merge +
// softmax + sparse PV unchanged (R12-R17 verified bit-exact).
// ---------------------------------------------------------------------------
__global__ __launch_bounds__(256, 2)
void attn_topk(const float* __restrict__ Qh, const float* __restrict__ Kh,
               const float* __restrict__ Vh, float* __restrict__ AO)
{
    __shared__ float Ls[4][64][LKEEP + 1];   // +1 pad: 13*4B lane stride
    __shared__ int   Li[4][64][LKEEP + 1];
    const int tid  = threadIdx.x;
    const int lane = tid & 63;
    const int w    = tid >> 6;          // 0..3 (key quarter / dim quarter)
    const int bh   = blockIdx.x;        // 0..31  (XCD = bh % 8)
    const int rg   = blockIdx.y;        // 0..31
    const int srow = rg * 64 + lane;    // this lane's query row
    const size_t hbase = (size_t)bh * SEQ * HDIM;
    const float* Q = Qh + hbase;
    const float* K = Kh + hbase;
    const float* V = Vh + hbase;

    // ---- this lane's q row -> VGPRs ----
    float q[64];
    {
        const float* qsrc = Q + (size_t)srow * HDIM;
        #pragma unroll
        for (int d4 = 0; d4 < 16; ++d4) {
            float4 t4 = *(const float4*)(qsrc + d4*4);
            q[d4*4+0]=t4.x; q[d4*4+1]=t4.y; q[d4*4+2]=t4.z; q[d4*4+3]=t4.w;
        }
    }

    // ---- FMA-prefilter lane-local top-LKEEP over this wave's 512 keys ----
    float fv[LKEEP]; int fi[LKEEP];
    #pragma unroll
    for (int s = 0; s < LKEEP; ++s) { fv[s] = -INFINITY; fi[s] = 0; }

    const int k0 = w * (SEQ/4);

    for (int c = 0; c < SEQ/4; ++c) {
        const float* kr = K + (size_t)(k0 + c) * HDIM;
        asm volatile("" : "+v"(kr));    // force VGPR addr -> VMEM (not s_load)
        float A0=0.f, A1=0.f, A2=0.f, A3=0.f;
        #pragma unroll
        for (int t = 0; t < 4; ++t) {       // stream 4 float4 per 16-dim block
            const float4 k0v = *(const float4*)(kr + t*16 + 0);
            const float4 k1v = *(const float4*)(kr + t*16 + 4);
            const float4 k2v = *(const float4*)(kr + t*16 + 8);
            const float4 k3v = *(const float4*)(kr + t*16 + 12);
            const int u = t*16;
            A0 = fmaf(q[u+ 0], k0v.x, A0);  A1 = fmaf(q[u+ 1], k0v.y, A1);
            A2 = fmaf(q[u+ 2], k0v.z, A2);  A3 = fmaf(q[u+ 3], k0v.w, A3);
            A0 = fmaf(q[u+ 4], k1v.x, A0);  A1 = fmaf(q[u+ 5], k1v.y, A1);
            A2 = fmaf(q[u+ 6], k1v.z, A2);  A3 = fmaf(q[u+ 7], k1v.w, A3);
            A0 = fmaf(q[u+ 8], k2v.x, A0);  A1 = fmaf(q[u+ 9], k2v.y, A1);
            A2 = fmaf(q[u+10], k2v.z, A2);  A3 = fmaf(q[u+11], k2v.w, A3);
            A0 = fmaf(q[u+12], k3v.x, A0);  A1 = fmaf(q[u+13], k3v.y, A1);
            A2 = fmaf(q[u+14], k3v.z, A2);  A3 = fmaf(q[u+15], k3v.w, A3);
        }
        const float cand = ((A0 + A1) + (A2 + A3)) * 0.125f;
        if (cand > fv[LKEEP-1]) {           // lane-local sorted insert
            float v = cand; int ix = k0 + c;
            #pragma unroll
            for (int s = 0; s < LKEEP; ++s) {
                const bool gt = v > fv[s];
                const float o1 = fv[s]; const int o2 = fi[s];
                fv[s] = gt ? v  : o1;  fi[s] = gt ? ix : o2;
                v     = gt ? o1 : v;   ix    = gt ? o2 : ix;
            }
        }
    }

    // ---- EXACT rescore (numpy npyv cascade) fused with canonical insert.
    //      Streams 4 float4 per t-block; candidate iterations fenced with
    //      sched_barrier(0) -> no cross-candidate gather hoisting (R15's
    //      spill). All tv/ti indexing static. ----
    float tv[LKEEP]; int ti[LKEEP];
    #pragma unroll
    for (int s = 0; s < LKEEP; ++s) { tv[s] = -INFINITY; ti[s] = 0x7fffffff; }

    #pragma unroll
    for (int s = 0; s < LKEEP; ++s) {
        const float* kr = K + (size_t)fi[s] * HDIM;
        float raw;
        {
            #pragma clang fp contract(off)
            float A0=0.f,A1=0.f,A2=0.f,A3=0.f;
            #pragma unroll
            for (int t = 0; t < 4; ++t) {
                const float4 kb0 = *(const float4*)(kr + t*16 + 0);
                const float4 kb1 = *(const float4*)(kr + t*16 + 4);
                const float4 kb2 = *(const float4*)(kr + t*16 + 8);
                const float4 kb3 = *(const float4*)(kr + t*16 + 12);
                const int u = t*16;
                A0 = q[u+0]*kb0.x + (q[u+4]*kb1.x + (q[u+8]*kb2.x  + (q[u+12]*kb3.x + A0)));
                A1 = q[u+1]*kb0.y + (q[u+5]*kb1.y + (q[u+9]*kb2.y  + (q[u+13]*kb3.y + A1)));
                A2 = q[u+2]*kb0.z + (q[u+6]*kb1.z + (q[u+10]*kb2.z + (q[u+14]*kb3.z + A2)));
                A3 = q[u+3]*kb0.w + (q[u+7]*kb1.w + (q[u+11]*kb2.w + (q[u+15]*kb3.w + A3)));
            }
            raw = (A0 + A1) + (A2 + A3);
        }
        float v = raw * 0.125f;          // exact npyv value, /sqrt(64) exact
        int  ix = fi[s];
        #pragma unroll
        for (int t = 0; t < LKEEP; ++t) {  // canonical insert (v desc, ix asc)
            const bool gt = (v > tv[t]) || (v == tv[t] && ix < ti[t]);
            const float otv = tv[t]; const int oti = ti[t];
            tv[t] = gt ? v  : otv;  ti[t] = gt ? ix  : oti;
            v     = gt ? otv : v;   ix    = gt ? oti : ix;
        }
        __builtin_amdgcn_sched_barrier(0);   // fence: no cross-candidate hoist
    }

    // ---- publish partial lists, one barrier ----
    #pragma unroll
    for (int s = 0; s < LKEEP; ++s) {
        Ls[w][lane][s] = tv[s];
        Li[w][lane][s] = ti[s];
    }
    __syncthreads();

    // ---- exact 4-way merge on EXACT values (pointer-walk, 10 steps) ----
    float gv[KKEEP]; int gi[KKEEP];
    {
        int   hp0 = 0, hp1 = 0, hp2 = 0, hp3 = 0;
        float hv0 = Ls[0][lane][0], hv1 = Ls[1][lane][0],
              hv2 = Ls[2][lane][0], hv3 = Ls[3][lane][0];
        int   hi0 = Li[0][lane][0], hi1 = Li[1][lane][0],
              hi2 = Li[2][lane][0], hi3 = Li[3][lane][0];
        #pragma unroll
        for (int s = 0; s < KKEEP; ++s) {
            float bv = hv0; int bi = hi0; int bj = 0;
            if (hv1 > bv || (hv1 == bv && hi1 < bi)) { bv = hv1; bi = hi1; bj = 1; }
            if (hv2 > bv || (hv2 == bv && hi2 < bi)) { bv = hv2; bi = hi2; bj = 2; }
            if (hv3 > bv || (hv3 == bv && hi3 < bi)) { bv = hv3; bi = hi3; bj = 3; }
            gv[s] = bv; gi[s] = bi;
            {
                const bool a = (bj == 0); const int np = hp0 + (a ? 1 : 0);
                const int  rp = np < LKEEP ? np : LKEEP-1;
                const float nv = Ls[0][lane][rp]; const int ni = Li[0][lane][rp];
                if (a) { hp0 = np; hv0 = (np < LKEEP) ? nv : -INFINITY; hi0 = ni; }
            }
            {
                const bool a = (bj == 1); const int np = hp1 + (a ? 1 : 0);
                const int  rp = np < LKEEP ? np : LKEEP-1;
                const float nv = Ls[1][lane][rp]; const int ni = Li[1][lane][rp];
                if (a) { hp1 = np; hv1 = (np < LKEEP) ? nv : -INFINITY; hi1 = ni; }
            }
            {
                const bool a = (bj == 2); const int np = hp2 + (a ? 1 : 0);
                const int  rp = np < LKEEP ? np : LKEEP-1;
                const float nv = Ls[2][lane][rp]; const int ni = Li[2][lane][rp];
                if (a) { hp2 = np; hv2 = (np < LKEEP) ? nv : -INFINITY; hi2 = ni; }
            }
            {
                const bool a = (bj == 3); const int np = hp3 + (a ? 1 : 0);
                const int  rp = np < LKEEP ? np : LKEEP-1;
                const float nv = Ls[3][lane][rp]; const int ni = Li[3][lane][rp];
                if (a) { hp3 = np; hv3 = (np < LKEEP) ? nv : -INFINITY; hi3 = ni; }
            }
        }
    }

    // ---- per-lane softmax over kept set (identical order to R6-R17) ----
    const float thr = gv[KTOP-1];
    const float m   = gv[0];
    float wv[KKEEP]; float wsum = 0.f;
    #pragma unroll
    for (int s = 0; s < KKEEP; ++s) {
        wv[s] = (gv[s] >= thr) ? expf(gv[s] - m) : 0.f;   // slots 8,9 iff tied
        wsum += wv[s];
    }

    // ---- sparse PV, this wave does dims [w*16, w*16+16) ----
    float o[16];
    #pragma unroll
    for (int d = 0; d < 16; ++d) o[d] = 0.f;
    #pragma unroll
    for (int s = 0; s < KKEEP; ++s) {
        const float wgt = wv[s] / wsum;                  // 0 for non-kept: exact
        const float* vrow = V + (size_t)gi[s] * HDIM + w * 16;
        #pragma unroll
        for (int d4 = 0; d4 < 4; ++d4) {
            float4 vv = *(const float4*)(vrow + d4*4);
            o[d4*4+0] = fmaf(wgt, vv.x, o[d4*4+0]);
            o[d4*4+1] = fmaf(wgt, vv.y, o[d4*4+1]);
            o[d4*4+2] = fmaf(wgt, vv.z, o[d4*4+2]);
            o[d4*4+3] = fmaf(wgt, vv.w, o[d4*4+3]);
        }
    }

    // AO flat layout [b][s][h*64+d]
    float* dst = AO + ((size_t)(bh >> 4) * SEQ + srow) * DMODEL
               + (bh & 15) * HDIM + w * 16;
    #pragma unroll
    for (int d4 = 0; d4 < 4; ++d4) {
        float4 ov; ov.x = o[d4*4+0]; ov.y = o[d4*4+1];
                   ov.z = o[d4*4+2]; ov.w = o[d4*4+3];
        *(float4*)(dst + d4*4) = ov;
    }
}

// ---------------------------------------------------------------------------
extern "C" void kernel_launch(void* const* d_in, const int* in_sizes, int n_in,
                              void* d_out, int out_size, void* d_ws, size_t ws_size,
                              hipStream_t stream)
{
    const float* q  = (const float*)d_in[0];
    const float* k  = (const float*)d_in[1];
    const float* v  = (const float*)d_in[2];
    const float* Wq = (const float*)d_in[3];
    const float* bq = (const float*)d_in[4];
    const float* Wk = (const float*)d_in[5];
    const float* bk = (const float*)d_in[6];
    const float* Wv = (const float*)d_in[7];
    const float* bv = (const float*)d_in[8];
    const float* Wo = (const float*)d_in[9];
    const float* bo = (const float*)d_in[10];
    float* out = (float*)d_out;

    const size_t nH = (size_t)BATCH * NHEAD * SEQ * HDIM;  // 4,194,304
    float* Qh = (float*)d_ws;          // 16.78 MB
    float* Kh = Qh + nH;               // 16.78 MB
    float* Vh = Kh + nH;               // 16.78 MB
    float* AO = Vh + nH;               // 16.78 MB  (total ~67 MB)

    dim3 gg(64, 16), gb(256);
    hipLaunchKernelGGL((proj_gemm<0>), gg, gb, 0, stream, q, Wq, bq, Qh);
    hipLaunchKernelGGL((proj_gemm<0>), gg, gb, 0, stream, k, Wk, bk, Kh);
    hipLaunchKernelGGL((proj_gemm<0>), gg, gb, 0, stream, v, Wv, bv, Vh);
    hipLaunchKernelGGL(attn_topk, dim3(BATCH*NHEAD, SEQ/64), dim3(256), 0, stream,
                       Qh, Kh, Vh, AO);
    hipLaunchKernelGGL((proj_gemm<1>), gg, gb, 0, stream, AO, Wo, bo, out);
}

// Round 20
// 990.306 us; speedup vs baseline: 1.8263x; 1.8263x over previous
//
#include <hip/hip_runtime.h>
#include <cmath>

#define BATCH  2
#define SEQ    2048
#define DMODEL 1024
#define NHEAD  16
#define HDIM   64
#define KTOP   8
#define LKEEP  12   // prefilter candidates per row (margin vs ~3e-4 pack error)
#define CHUNK  32   // keys per staged LDS chunk
#define NCHUNK 32   // 1024 keys per wave / CHUNK

// KC=512 CONFIRMED bit-exact vs harness numpy reference (rounds 6/8-19 pass).
#define KC_PANEL 512

typedef float v2f __attribute__((ext_vector_type(2)));

// ---------------------------------------------------------------------------
// Projection GEMM replicating OpenBLAS sgemm fp32 rounding (KC=512 panels).
// MODE 0: out in head layout [b][h][s][d]; MODE 1: flat [row][col].
// ---------------------------------------------------------------------------
template<int MODE>
__global__ __launch_bounds__(256)
void proj_gemm(const float* __restrict__ A, const float* __restrict__ W,
               const float* __restrict__ bias, float* __restrict__ outp)
{
    __shared__ float As[32][68];   // [k][m]
    __shared__ float Bs[32][68];   // [k][n]
    const int tid  = threadIdx.x;
    const int tx   = tid & 15, ty = tid >> 4;
    const int row0 = blockIdx.x * 64;
    const int col0 = blockIdx.y * 64;
    const int lm   = tid >> 2;          // 0..63
    const int lk   = (tid & 3) * 8;     // 0,8,16,24

    float acc[4][4] = {};   // open panel chain
    float sum[4][4] = {};   // closed panels

    for (int kb = 0; kb < DMODEL; kb += 32) {
        if (kb && (kb % KC_PANEL == 0)) {
            #pragma unroll
            for (int i = 0; i < 4; ++i)
                #pragma unroll
                for (int j = 0; j < 4; ++j) { sum[i][j] += acc[i][j]; acc[i][j] = 0.f; }
        }
        __syncthreads();
        const float* srcA = A + (size_t)(row0 + lm) * DMODEL + kb + lk;
        float4 a0 = *(const float4*)srcA;
        float4 a1 = *(const float4*)(srcA + 4);
        const float* srcB = W + (size_t)(col0 + lm) * DMODEL + kb + lk;
        float4 b0 = *(const float4*)srcB;
        float4 b1 = *(const float4*)(srcB + 4);
        As[lk+0][lm]=a0.x; As[lk+1][lm]=a0.y; As[lk+2][lm]=a0.z; As[lk+3][lm]=a0.w;
        As[lk+4][lm]=a1.x; As[lk+5][lm]=a1.y; As[lk+6][lm]=a1.z; As[lk+7][lm]=a1.w;
        Bs[lk+0][lm]=b0.x; Bs[lk+1][lm]=b0.y; Bs[lk+2][lm]=b0.z; Bs[lk+3][lm]=b0.w;
        Bs[lk+4][lm]=b1.x; Bs[lk+5][lm]=b1.y; Bs[lk+6][lm]=b1.z; Bs[lk+7][lm]=b1.w;
        __syncthreads();
        #pragma unroll
        for (int kk = 0; kk < 32; ++kk) {   // ascending k, fused-FMA chain
            float4 af = *(const float4*)&As[kk][ty*4];
            float4 bf = *(const float4*)&Bs[kk][tx*4];
            float a_[4] = {af.x, af.y, af.z, af.w};
            float b_[4] = {bf.x, bf.y, bf.z, bf.w};
            #pragma unroll
            for (int i = 0; i < 4; ++i)
                #pragma unroll
                for (int j = 0; j < 4; ++j)
                    acc[i][j] = fmaf(a_[i], b_[j], acc[i][j]);
        }
    }

    #pragma unroll
    for (int i = 0; i < 4; ++i) {
        const int row = row0 + ty*4 + i;
        const int bb  = row >> 11;
        const int ss  = row & (SEQ - 1);
        #pragma unroll
        for (int j = 0; j < 4; ++j) {
            const int col = col0 + tx*4 + j;
            float r = sum[i][j] + acc[i][j];   // close final panel
            r = r + bias[col];                 // bias == 0.0f: exact
            if constexpr (MODE == 1) {
                outp[(size_t)row * DMODEL + col] = r;
            } else {
                const int h = col >> 6, d = col & 63;
                outp[(((size_t)(bb*NHEAD + h))*SEQ + ss)*HDIM + d] = r;
            }
        }
    }
}

// ---------------------------------------------------------------------------
// Attention, lane = query row. Block = 2 waves x 64 lanes (same 64 rows);
// wave w scans keys [w*1024, (w+1)*1024) in 32-key chunks staged into a
// PRIVATE LDS buffer via global_load_lds (async DMA, no VGPR/SGPR roundtrip,
// counted by vmcnt):
//   - R14/16/17: scalar K loads serialize (lgkmcnt full drains, sL1 thrash).
//   - R19: VMEM broadcast exposes full latency (no reg budget for prefetch).
//   - Here: process chunk c (~5k cyc) covers chunk c+1's DMA; the explicit
//     vmcnt(0) at chunk head waits data issued a whole chunk ago (~0 cost).
//     Single 8KB buffer/wave: lgkmcnt(0) before restage ensures ds_reads
//     landed. No barriers in the scan; no scalar path.
// Scan math: v2f pk-FMA prefilter (order-free), packed-u32 top-12
//   (sign-flipped float bits | 11-bit key idx; insert = 2-op max/min chain;
//   truncation ~3e-4 << rank gaps -> P(lose a true top-8) ~ 0.007 dataset).
// Then: packed-domain 2-way merge (LDS pointer-walk), EXACT npyv rescore of
// the 12 candidates (bit-exact numpy values), canonical sort, softmax over
// kept set (>= 8th, ties incl.), sparse PV split by dim-half per wave.
// Occupancy: 1024 blocks x 2 waves = 2 waves/SIMD; VGPR target <=128.
// ---------------------------------------------------------------------------
__global__ __launch_bounds__(128, 2)
void attn_topk(const float* __restrict__ Qh, const float* __restrict__ Kh,
               const float* __restrict__ Vh, float* __restrict__ AO)
{
    __shared__ float    Ks[2][CHUNK * HDIM];     // 2 x 8KB, per-wave private
    __shared__ uint32_t Lp[2][64][LKEEP + 1];    // packed publish (pad 13)
    const int tid  = threadIdx.x;
    const int lane = tid & 63;
    const int w    = tid >> 6;          // 0..1 (key half / dim half)
    const int rg   = blockIdx.x;        // 0..31
    const int bh   = blockIdx.y;        // 0..31
    const int srow = rg * 64 + lane;    // this lane's query row
    const size_t hbase = (size_t)bh * SEQ * HDIM;
    const float* Q = Qh + hbase;
    const float* K = Kh + hbase;
    const float* V = Vh + hbase;

    // ---- this lane's q row -> v2f VGPR pairs (64 regs) ----
    v2f q2[32];
    {
        const float* qsrc = Q + (size_t)srow * HDIM;
        #pragma unroll
        for (int i = 0; i < 16; ++i) {
            float4 t = *(const float4*)(qsrc + i*4);
            q2[2*i+0] = (v2f){t.x, t.y};
            q2[2*i+1] = (v2f){t.z, t.w};
        }
    }

    // ---- packed lane-local top-LKEEP (u32: value-bits | key index) ----
    uint32_t tp[LKEEP];
    #pragma unroll
    for (int s = 0; s < LKEEP; ++s) tp[s] = 0u;

    const int kbase = w * (SEQ/2);
    float* myKs = &Ks[w][0];

    // ---- prologue: stage chunk 0 (one global_load_lds per key: 64x4B) ----
    #pragma unroll
    for (int j = 0; j < CHUNK; ++j)
        __builtin_amdgcn_global_load_lds(
            (const __attribute__((address_space(1))) void*)(K + (size_t)(kbase + j)*HDIM + lane),
            (__attribute__((address_space(3))) void*)(myKs + j*HDIM), 4, 0, 0);

    for (int c = 0; c < NCHUNK; ++c) {
        // chunk c's DMA was issued one full chunk of compute ago -> ~free
        asm volatile("s_waitcnt vmcnt(0)" ::: "memory");
        __builtin_amdgcn_sched_barrier(0);

        #pragma unroll 4
        for (int j = 0; j < CHUNK; ++j) {
            const float4* kb4 = (const float4*)(myKs + j*HDIM);
            v2f A0 = (v2f){0.f, 0.f}, A1 = (v2f){0.f, 0.f};
            #pragma unroll
            for (int t = 0; t < 16; ++t) {     // 16 x ds_read_b128 broadcast
                const float4 kk = kb4[t];
                A0 += q2[2*t+0] * (v2f){kk.x, kk.y};   // pk-FMA (order-free)
                A1 += q2[2*t+1] * (v2f){kk.z, kk.w};
            }
            const v2f S = A0 + A1;
            const float cand = (S.x + S.y) * 0.125f;   // /sqrt(64)
            uint32_t vb = __float_as_uint(cand);
            vb ^= (uint32_t)((int32_t)vb >> 31) | 0x80000000u;  // monotonic map
            const uint32_t pk = (vb & 0xFFFFF800u) | (uint32_t)(kbase + c*CHUNK + j);
            if (pk > tp[LKEEP-1]) {            // 2-op/slot max/min shift chain
                uint32_t v = pk;
                #pragma unroll
                for (int s = 0; s < LKEEP; ++s) {
                    const uint32_t hi = v > tp[s] ? v : tp[s];
                    const uint32_t lo = v > tp[s] ? tp[s] : v;
                    tp[s] = hi; v = lo;
                }
            }
        }

        if (c + 1 < NCHUNK) {
            // all ds_read returns landed before DMA may overwrite the buffer
            asm volatile("s_waitcnt lgkmcnt(0)" ::: "memory");
            __builtin_amdgcn_sched_barrier(0);
            const int kc = kbase + (c+1)*CHUNK;
            #pragma unroll
            for (int j = 0; j < CHUNK; ++j)
                __builtin_amdgcn_global_load_lds(
                    (const __attribute__((address_space(1))) void*)(K + (size_t)(kc + j)*HDIM + lane),
                    (__attribute__((address_space(3))) void*)(myKs + j*HDIM), 4, 0, 0);
        }
    }

    // ---- publish packed lists; one barrier; 2-way merge in packed domain ----
    #pragma unroll
    for (int s = 0; s < LKEEP; ++s) Lp[w][lane][s] = tp[s];
    __syncthreads();

    uint32_t mg[LKEEP];
    {
        const uint32_t* la = &Lp[w][lane][0];      // LDS: dynamic idx is fine
        const uint32_t* lb = &Lp[w ^ 1][lane][0];
        int pa = 0, pb = 0;
        #pragma unroll
        for (int s = 0; s < LKEEP; ++s) {
            const uint32_t va = la[pa], vb2 = lb[pb];
            const bool ta = va > vb2;              // ties impossible (idx bits)
            mg[s] = ta ? va : vb2;
            pa += ta ? 1 : 0;
            pb += ta ? 0 : 1;
        }
    }

    // ---- EXACT rescore (numpy npyv cascade) + canonical sort (v desc, ix asc)
    float tv[LKEEP]; int ti[LKEEP];
    #pragma unroll
    for (int s = 0; s < LKEEP; ++s) { tv[s] = -INFINITY; ti[s] = 0x7fffffff; }

    #pragma unroll
    for (int s = 0; s < LKEEP; ++s) {
        const int ks = (int)(mg[s] & 0x7FFu);
        const float* kr = K + (size_t)ks * HDIM;
        float raw;
        {
            #pragma clang fp contract(off)
            float A0=0.f,A1=0.f,A2=0.f,A3=0.f;
            #pragma unroll
            for (int t = 0; t < 4; ++t) {
                const float4 kb0 = *(const float4*)(kr + t*16 + 0);
                const float4 kb1 = *(const float4*)(kr + t*16 + 4);
                const float4 kb2 = *(const float4*)(kr + t*16 + 8);
                const float4 kb3 = *(const float4*)(kr + t*16 + 12);
                const int u = t*16;
                A0 = q2[u/2+0].x*kb0.x + (q2[u/2+2].x*kb1.x + (q2[u/2+4].x*kb2.x + (q2[u/2+6].x*kb3.x + A0)));
                A1 = q2[u/2+0].y*kb0.y + (q2[u/2+2].y*kb1.y + (q2[u/2+4].y*kb2.y + (q2[u/2+6].y*kb3.y + A1)));
                A2 = q2[u/2+1].x*kb0.z + (q2[u/2+3].x*kb1.z + (q2[u/2+5].x*kb2.z + (q2[u/2+7].x*kb3.z + A2)));
                A3 = q2[u/2+1].y*kb0.w + (q2[u/2+3].y*kb1.w + (q2[u/2+5].y*kb2.w + (q2[u/2+7].y*kb3.w + A3)));
            }
            raw = (A0 + A1) + (A2 + A3);
        }
        float v = raw * 0.125f;          // exact npyv value, /sqrt(64) exact
        int  ix = ks;
        #pragma unroll
        for (int t = 0; t < LKEEP; ++t) {
            const bool gt = (v > tv[t]) || (v == tv[t] && ix < ti[t]);
            const float otv = tv[t]; const int oti = ti[t];
            tv[t] = gt ? v  : otv;  ti[t] = gt ? ix  : oti;
            v     = gt ? otv : v;   ix    = gt ? oti : ix;
        }
        __builtin_amdgcn_sched_barrier(0);   // no cross-candidate gather hoist
    }

    // ---- per-lane softmax over kept set (>= 8th value, ties included) ----
    const float thr = tv[KTOP-1];
    const float m   = tv[0];
    float wv[LKEEP]; float wsum = 0.f;
    #pragma unroll
    for (int s = 0; s < LKEEP; ++s) {
        wv[s] = (tv[s] >= thr) ? expf(tv[s] - m) : 0.f;
        wsum += wv[s];
    }

    // ---- sparse PV, this wave does dims [w*32, w*32+32) ----
    float o[32];
    #pragma unroll
    for (int d = 0; d < 32; ++d) o[d] = 0.f;
    #pragma unroll
    for (int s = 0; s < LKEEP; ++s) {
        const float wgt = wv[s] / wsum;              // 0 for non-kept: exact
        const float* vrow = V + (size_t)ti[s] * HDIM + w * 32;
        #pragma unroll
        for (int d4 = 0; d4 < 8; ++d4) {
            const float4 vvv = *(const float4*)(vrow + d4*4);
            o[d4*4+0] = fmaf(wgt, vvv.x, o[d4*4+0]);
            o[d4*4+1] = fmaf(wgt, vvv.y, o[d4*4+1]);
            o[d4*4+2] = fmaf(wgt, vvv.z, o[d4*4+2]);
            o[d4*4+3] = fmaf(wgt, vvv.w, o[d4*4+3]);
        }
    }

    // AO flat layout [b][s][h*64+d]
    float* dst = AO + ((size_t)(bh >> 4) * SEQ + srow) * DMODEL
               + (bh & 15) * HDIM + w * 32;
    #pragma unroll
    for (int d4 = 0; d4 < 8; ++d4) {
        float4 ov; ov.x = o[d4*4+0]; ov.y = o[d4*4+1];
                   ov.z = o[d4*4+2]; ov.w = o[d4*4+3];
        *(float4*)(dst + d4*4) = ov;
    }
}

// ---------------------------------------------------------------------------
extern "C" void kernel_launch(void* const* d_in, const int* in_sizes, int n_in,
                              void* d_out, int out_size, void* d_ws, size_t ws_size,
                              hipStream_t stream)
{
    const float* q  = (const float*)d_in[0];
    const float* k  = (const float*)d_in[1];
    const float* v  = (const float*)d_in[2];
    const float* Wq = (const float*)d_in[3];
    const float* bq = (const float*)d_in[4];
    const float* Wk = (const float*)d_in[5];
    const float* bk = (const float*)d_in[6];
    const float* Wv = (const float*)d_in[7];
    const float* bv = (const float*)d_in[8];
    const float* Wo = (const float*)d_in[9];
    const float* bo = (const float*)d_in[10];
    float* out = (float*)d_out;

    const size_t nH = (size_t)BATCH * NHEAD * SEQ * HDIM;  // 4,194,304
    float* Qh = (float*)d_ws;          // 16.78 MB
    float* Kh = Qh + nH;               // 16.78 MB
    float* Vh = Kh + nH;               // 16.78 MB
    float* AO = Vh + nH;               // 16.78 MB  (total ~67 MB)

    dim3 gg(64, 16), gb(256);
    hipLaunchKernelGGL((proj_gemm<0>), gg, gb, 0, stream, q, Wq, bq, Qh);
    hipLaunchKernelGGL((proj_gemm<0>), gg, gb, 0, stream, k, Wk, bk, Kh);
    hipLaunchKernelGGL((proj_gemm<0>), gg, gb, 0, stream, v, Wv, bv, Vh);
    hipLaunchKernelGGL(attn_topk, dim3(SEQ/64, BATCH*NHEAD), dim3(128), 0, stream,
                       Qh, Kh, Vh, AO);
    hipLaunchKernelGGL((proj_gemm<1>), gg, gb, 0, stream, AO, Wo, bo, out);
}